// Round 10
// baseline (315.767 us; speedup 1.0000x reference)
//
#include <hip/hip_runtime.h>
#include <hip/hip_cooperative_groups.h>

namespace cg = cooperative_groups;

#define Bv   2
#define Nv   8192
#define Cv   128
#define KSv  120
#define KNNv 30

// ---------------------------------------------------------------------------
// Compile-time replication of np.random.RandomState(1234).shuffle(arange(8192))
// -> first 120 entries. MT19937 + Fisher-Yates with masked rejection.
// ---------------------------------------------------------------------------
namespace mtns {
struct MTState { unsigned mt[624]; int mti; };
constexpr void mt_seed(MTState& s, unsigned seed) {
  for (int pos = 0; pos < 624; ++pos) {
    s.mt[pos] = seed;
    seed = 1812433253u * (seed ^ (seed >> 30)) + (unsigned)pos + 1u;
  }
  s.mti = 624;
}
constexpr unsigned mt_next(MTState& s) {
  if (s.mti >= 624) {
    for (int i = 0; i < 624; ++i) {
      unsigned y = (s.mt[i] & 0x80000000u) | (s.mt[(i + 1) % 624] & 0x7fffffffu);
      unsigned v = s.mt[(i + 397) % 624] ^ (y >> 1);
      s.mt[i] = (y & 1u) ? (v ^ 0x9908b0dfu) : v;
    }
    s.mti = 0;
  }
  unsigned y = s.mt[s.mti++];
  y ^= y >> 11;
  y ^= (y << 7) & 0x9d2c5680u;
  y ^= (y << 15) & 0xefc60000u;
  y ^= y >> 18;
  return y;
}
struct IdxTable { int v[KSv]; };
constexpr IdxTable make_idx() {
  MTState st{};
  mt_seed(st, 1234u);
  int arr[Nv] = {};
  for (int i = 0; i < Nv; ++i) arr[i] = i;
  for (int i = Nv - 1; i > 0; --i) {
    unsigned mask = (unsigned)i;
    mask |= mask >> 1; mask |= mask >> 2; mask |= mask >> 4;
    mask |= mask >> 8; mask |= mask >> 16;
    unsigned j = 0;
    do { j = mt_next(st) & mask; } while (j > (unsigned)i);
    int tmp = arr[i]; arr[i] = arr[(int)j]; arr[(int)j] = tmp;
  }
  IdxTable out{};
  for (int k = 0; k < KSv; ++k) out.v[k] = arr[k];
  return out;
}
}  // namespace mtns

__constant__ mtns::IdxTable IDX = mtns::make_idx();

__device__ __forceinline__ float wave_sum(float v) {
  #pragma unroll
  for (int m = 32; m; m >>= 1) v += __shfl_xor(v, m);
  return v;
}

// Opaque barrier: keeps x*x and the add as SEPARATE f32 roundings (numpy does
// mult-then-add, no FMA, in pairwise_sum) despite contraction.
__device__ __forceinline__ float opaque(float x) {
  asm volatile("" : "+v"(x));
  return x;
}

// Wave-uniform broadcasts on the VALU path (ignores exec mask).
__device__ __forceinline__ float rdf(float v, int k) {
  return __int_as_float(__builtin_amdgcn_readlane(__float_as_int(v), k));
}
__device__ __forceinline__ int rdi(int v, int k) {
  return __builtin_amdgcn_readlane(v, k);
}
__device__ __forceinline__ unsigned long long rdull(unsigned long long v, int k) {
  unsigned lo = (unsigned)__builtin_amdgcn_readlane((int)(unsigned)(v & 0xFFFFFFFFull), k);
  unsigned hi = (unsigned)__builtin_amdgcn_readlane((int)(unsigned)(v >> 32), k);
  return (((unsigned long long)hi) << 32) | lo;
}

// Order-isomorphic u64 sort key for (dist desc, index asc) stable rank:
// key_j > key_i  <=>  d_j > d_i || (d_j == d_i && j < i).
// ord32 is the standard monotone f32->u32 map; +/-0 mix impossible here
// (d = dot - 1.0f can only produce +0), no NaNs.
__device__ __forceinline__ unsigned long long mkkey(float d, int t) {
  unsigned u = __float_as_uint(d);
  unsigned m = (unsigned)((int)u >> 31);
  unsigned o = u ^ (m | 0x80000000u);
  return (((unsigned long long)o) << 7) | (unsigned)(119 - t);
}

// npyv reduce tree (identical op order to verified R4/R7/R8 kernels)
__device__ __forceinline__ float npyv_reduce(const float4* a) {
  float4 h0, h1, h;
  h0.x = a[0].x + a[2].x; h0.y = a[0].y + a[2].y;
  h0.z = a[0].z + a[2].z; h0.w = a[0].w + a[2].w;
  h1.x = a[1].x + a[3].x; h1.y = a[1].y + a[3].y;
  h1.z = a[1].z + a[3].z; h1.w = a[1].w + a[3].w;
  h.x = h0.x + h1.x; h.y = h0.y + h1.y; h.z = h0.z + h1.z; h.w = h0.w + h1.w;
  float sx = h.x + h.z;
  float sy = h.y + h.w;
  return sx + sy;
}

// ---------------------------------------------------------------------------
// Single cooperative kernel. 256 blocks x 512 threads (8 waves), 1 block/CU.
// Phase 0: blocks 0..239 prep one sampled row (gn32 + G)    [k0, bit-exact]
// grid.sync
// Phase 1: stage gnS (XOR swizzle) for this block's batch
// Phase 2: 4 row-pairs per wave: paired npyv dots, u64-key readlane rank,
//          W1/W2 readlane MLP, shuffle softmax, y-scan -> msel (LDS) +
//          GN partials (regs)
// grid.sync
// Phase 3: every block reduces ALL 128 block-partials of its batch
//          (2 per lane, fixed-order f64, deterministic) -> stats in LDS
//          [R9 BUG FIX: only 64 of 128 partials were summed]
// Phase 4: GN affine + leaky + 3x256 output MLP from LDS msel  [k4 fused]
// ---------------------------------------------------------------------------
__global__ __launch_bounds__(512, 2) void k_all(
    const float* __restrict__ points,
    const float* __restrict__ feature,
    const float* __restrict__ inst,
    const float* __restrict__ w1,
    const float* __restrict__ w2,
    const float* __restrict__ conv_w,
    const float* __restrict__ gamma,
    const float* __restrict__ beta,
    const float* __restrict__ mlp_w,
    const float* __restrict__ mlp_b,
    float* __restrict__ gn32,
    float* __restrict__ GW,
    float2* __restrict__ part,
    float* __restrict__ out) {
  __shared__ float4 gnS[KSv * 32];       // 61440 B
  __shared__ float sc[8 * 384];          // 12288 B per-wave scratch
  __shared__ float2 mselS[8][8][64];     // 32768 B: [wave][row][lane]
  __shared__ float2 partS[16];
  __shared__ float2 statsS[2];

  int bid = blockIdx.x;
  int tid = threadIdx.x;
  int w = tid >> 6, l = tid & 63;
  cg::grid_group grid = cg::this_grid();

  // ---------------- Phase 0: prep (bit-identical to verified k0) ----------
  if (bid < Bv * KSv) {
    int b0 = bid / KSv, kp = bid % KSv;
    int jg = IDX.v[kp];
    float* rowS = sc;            // 128
    float* featS = sc + 128;     // 128
    float* ptS = sc + 256;       // 3
    float* nAcc = sc + 260;      // 8
    float* nrmP = sc + 268;      // 1
    long rowi = (long)b0 * Nv + jg;
    if (tid < Cv) {
      rowS[tid] = inst[rowi * Cv + tid];
      featS[tid] = feature[rowi * Cv + tid];
      if (tid < 3) ptS[tid] = points[rowi * 3 + tid];
    }
    __syncthreads();
    if (tid < 8) {
      float x0 = rowS[tid];
      float acc = opaque(x0 * x0);
      #pragma unroll
      for (int i = 1; i < 16; ++i) {
        float xv = rowS[8 * i + tid];
        acc = acc + opaque(xv * xv);
      }
      nAcc[tid] = acc;
    }
    __syncthreads();
    if (tid == 0) {
      float res = ((nAcc[0] + nAcc[1]) + (nAcc[2] + nAcc[3])) +
                  ((nAcc[4] + nAcc[5]) + (nAcc[6] + nAcc[7]));
      nrmP[0] = sqrtf(res);
    }
    __syncthreads();
    if (tid < Cv) {
      float iv = rowS[tid];
      gn32[(b0 * KSv + kp) * Cv + tid] = iv / nrmP[0];   // IEEE f32 div
      const float* cw = conv_w + tid * 131;
      float acc = 0.f;
      #pragma unroll 8
      for (int c = 0; c < Cv; ++c) acc = fmaf(featS[c], cw[c], acc);
      acc = fmaf(ptS[0], cw[128],
                 fmaf(ptS[1], cw[129], fmaf(ptS[2], cw[130], acc)));
      GW[(b0 * KSv + kp) * Cv + tid] = acc;
    }
  }
  __threadfence();
  grid.sync();

  // ---------------- Phase 1: stage gnS (XOR swizzle) ----------------------
  int b = bid >> 7;                      // 128 blocks per batch
  int blocal = bid & 127;                // 64 rows per block
  const float4* gnG = (const float4*)(gn32 + (long)b * KSv * Cv);
  for (int i = tid; i < KSv * 32; i += 512) {
    int kp = i >> 5, c4 = i & 31;
    gnS[kp * 32 + (c4 ^ (kp & 31))] = gnG[i];
  }
  __syncthreads();

  float* wb = sc + w * 384;              // wave-private scratch
  float* fnA = wb;                       // 128
  float* fnB = wb + 128;                 // 128
  float* tvA = wb + 256; int* tiA = (int*)(wb + 288);
  float* tvB = wb + 320; int* tiB = (int*)(wb + 352);

  int c0 = 2 * l, c1 = 2 * l + 1;
  float ga0 = gamma[c0], ga1 = gamma[c1];
  float cwa0 = conv_w[c0 * 131 + 128], cwb0 = conv_w[c0 * 131 + 129],
        cwc0 = conv_w[c0 * 131 + 130];
  float cwa1 = conv_w[c1 * 131 + 128], cwb1 = conv_w[c1 * 131 + 129],
        cwc1 = conv_w[c1 * 131 + 130];
  const float* Gb = GW + (long)b * KSv * Cv;
  const float NINF = -__builtin_inff();
  float sAcc = 0.f, qAcc = 0.f;

  // ---------------- Phase 2: 4 row-pairs per wave -------------------------
  #pragma clang loop unroll(disable)
  for (int pe = 0; pe < 4; ++pe) {
    int nA = blocal * 64 + w * 8 + pe * 2;
    long rowA = (long)b * Nv + nA;
    long rowB = rowA + 1;
    __builtin_amdgcn_wave_barrier();
    float2 ivA = *(const float2*)(inst + rowA * Cv + c0);
    float2 ivB = *(const float2*)(inst + rowB * Cv + c0);
    ((float2*)fnA)[l] = ivA;
    ((float2*)fnB)[l] = ivB;
    __builtin_amdgcn_wave_barrier();
    // numpy pairwise norms: lanes 0-7 -> A, 8-15 -> B (verified R8 pattern)
    float acc = 0.f;
    if (l < 16) {
      const float* xr = (l < 8) ? fnA : fnB;
      int j = l & 7;
      float x0 = xr[j];
      acc = opaque(x0 * x0);
      #pragma unroll
      for (int i = 1; i < 16; ++i) {
        float xv = xr[8 * i + j];
        acc = acc + opaque(xv * xv);
      }
    }
    float nrmA = sqrtf(((rdf(acc, 0) + rdf(acc, 1)) + (rdf(acc, 2) + rdf(acc, 3))) +
                       ((rdf(acc, 4) + rdf(acc, 5)) + (rdf(acc, 6) + rdf(acc, 7))));
    float nrmB = sqrtf(((rdf(acc, 8) + rdf(acc, 9)) + (rdf(acc, 10) + rdf(acc, 11))) +
                       ((rdf(acc, 12) + rdf(acc, 13)) + (rdf(acc, 14) + rdf(acc, 15))));
    __builtin_amdgcn_wave_barrier();
    float2 fA2, fB2;
    fA2.x = ivA.x / nrmA; fA2.y = ivA.y / nrmA;
    fB2.x = ivB.x / nrmB; fB2.y = ivB.y / nrmB;
    ((float2*)fnA)[l] = fA2;
    ((float2*)fnB)[l] = fB2;
    __builtin_amdgcn_wave_barrier();

    // paired npyv dots (per-dist op order identical to verified kernels)
    const float4* fA4 = (const float4*)fnA;
    const float4* fB4 = (const float4*)fnB;
    int sw = l & 31;
    const float4* g0r = gnS + l * 32;
    int r1 = 64 + l; if (r1 > KSv - 1) r1 = KSv - 1;
    const float4* g1r = gnS + r1 * 32;
    float4 aA0[4], aA1[4], aB0[4], aB1[4];
    #pragma unroll
    for (int i = 0; i < 4; ++i) {
      aA0[i] = float4{0,0,0,0}; aA1[i] = float4{0,0,0,0};
      aB0[i] = float4{0,0,0,0}; aB1[i] = float4{0,0,0,0};
    }
    #pragma unroll 4
    for (int c4 = 0; c4 < 32; ++c4) {
      float4 fa = fA4[c4];
      float4 fb = fB4[c4];
      float4 g0 = g0r[c4 ^ sw];
      float4 g1 = g1r[c4 ^ sw];
      int m = c4 & 3;
      aA0[m].x = fmaf(g0.x, fa.x, aA0[m].x); aA0[m].y = fmaf(g0.y, fa.y, aA0[m].y);
      aA0[m].z = fmaf(g0.z, fa.z, aA0[m].z); aA0[m].w = fmaf(g0.w, fa.w, aA0[m].w);
      aB0[m].x = fmaf(g0.x, fb.x, aB0[m].x); aB0[m].y = fmaf(g0.y, fb.y, aB0[m].y);
      aB0[m].z = fmaf(g0.z, fb.z, aB0[m].z); aB0[m].w = fmaf(g0.w, fb.w, aB0[m].w);
      aA1[m].x = fmaf(g1.x, fa.x, aA1[m].x); aA1[m].y = fmaf(g1.y, fa.y, aA1[m].y);
      aA1[m].z = fmaf(g1.z, fa.z, aA1[m].z); aA1[m].w = fmaf(g1.w, fa.w, aA1[m].w);
      aB1[m].x = fmaf(g1.x, fb.x, aB1[m].x); aB1[m].y = fmaf(g1.y, fb.y, aB1[m].y);
      aB1[m].z = fmaf(g1.z, fb.z, aB1[m].z); aB1[m].w = fmaf(g1.w, fb.w, aB1[m].w);
    }
    float d0A = npyv_reduce(aA0) - 1.0f;
    float d1A = npyv_reduce(aA1) - 1.0f;
    float d0B = npyv_reduce(aB0) - 1.0f;
    float d1B = npyv_reduce(aB1) - 1.0f;

    // u64 sort keys; invalid slot1 (l>=56) = 0 (below every real key)
    unsigned long long kA0 = mkkey(d0A, l);
    unsigned long long kB0 = mkkey(d0B, l);
    unsigned long long kA1 = (l < 56) ? mkkey(d1A, 64 + l) : 0ull;
    unsigned long long kB1 = (l < 56) ? mkkey(d1B, 64 + l) : 0ull;

    // all-pairs stable rank via readlane rotation (VALU only, zero DS)
    int rkA0 = 0, rkA1 = 0, rkB0 = 0, rkB1 = 0;
    for (int j = 0; j < 64; ++j) {
      unsigned long long a0 = rdull(kA0, j);
      unsigned long long a1 = rdull(kA1, j);
      unsigned long long b0 = rdull(kB0, j);
      unsigned long long b1 = rdull(kB1, j);
      rkA0 += (a0 > kA0); rkA0 += (a1 > kA0);
      rkA1 += (a0 > kA1); rkA1 += (a1 > kA1);
      rkB0 += (b0 > kB0); rkB0 += (b1 > kB0);
      rkB1 += (b0 > kB1); rkB1 += (b1 > kB1);
    }
    if (rkA0 < KNNv) { tvA[rkA0] = d0A; tiA[rkA0] = l; }
    if (l < 56 && rkA1 < KNNv) { tvA[rkA1] = d1A; tiA[rkA1] = 64 + l; }
    if (rkB0 < KNNv) { tvB[rkB0] = d0B; tiB[rkB0] = l; }
    if (l < 56 && rkB1 < KNNv) { tvB[rkB1] = d1B; tiB[rkB1] = 64 + l; }
    __builtin_amdgcn_wave_barrier();
    float mytvA = 0.f, mytvB = 0.f;
    int mytiA = 0, mytiB = 0;
    if (l < KNNv) {
      mytvA = tvA[l]; mytiA = tiA[l];
      mytvB = tvB[l]; mytiB = tiB[l];
    }

    // a = relu(W1 . topk); a2 = W2 . a (readlane broadcasts; verified R8)
    float aA = 0.f, aB = 0.f;
    if (l < KNNv) {
      const float* w1r = w1 + l * KNNv;
      #pragma unroll 6
      for (int k = 0; k < KNNv; ++k) {
        float w1k = w1r[k];
        aA = fmaf(rdf(mytvA, k), w1k, aA);
        aB = fmaf(rdf(mytvB, k), w1k, aB);
      }
      aA = fmaxf(aA, 0.f);
      aB = fmaxf(aB, 0.f);
    }
    float a2A = NINF, a2B = NINF;
    if (l < KNNv) {
      const float* w2r = w2 + l * KNNv;
      float sA2 = 0.f, sB2 = 0.f;
      #pragma unroll 6
      for (int o = 0; o < KNNv; ++o) {
        float w2o = w2r[o];
        sA2 = fmaf(rdf(aA, o), w2o, sA2);
        sB2 = fmaf(rdf(aB, o), w2o, sB2);
      }
      a2A = sA2; a2B = sB2;
    }

    // softmax over 30 (shuffle trees; verified R8)
    float mA = a2A, mB = a2B;
    #pragma unroll
    for (int msk = 32; msk; msk >>= 1) {
      mA = fmaxf(mA, __shfl_xor(mA, msk));
      mB = fmaxf(mB, __shfl_xor(mB, msk));
    }
    float evA = (l < KNNv) ? __expf(a2A - mA) : 0.f;
    float evB = (l < KNNv) ? __expf(a2B - mB) : 0.f;
    float invA = 1.0f / wave_sum(evA);
    float invB = 1.0f / wave_sum(evB);
    float atpA = evA * invA;
    float atpB = evB * invB;

    // y scan (verified R8)
    float pA0 = points[rowA * 3 + 0], pA1 = points[rowA * 3 + 1],
          pA2 = points[rowA * 3 + 2];
    float pB0 = points[rowB * 3 + 0], pB1 = points[rowB * 3 + 1],
          pB2 = points[rowB * 3 + 2];
    float pwA0 = fmaf(pA0, cwa0, fmaf(pA1, cwb0, pA2 * cwc0));
    float pwA1 = fmaf(pA0, cwa1, fmaf(pA1, cwb1, pA2 * cwc1));
    float pwB0 = fmaf(pB0, cwa0, fmaf(pB1, cwb0, pB2 * cwc0));
    float pwB1 = fmaf(pB0, cwa1, fmaf(pB1, cwb1, pB2 * cwc1));
    float mxA0 = NINF, mnA0 = -NINF, mxA1 = NINF, mnA1 = -NINF;
    float mxB0 = NINF, mnB0 = -NINF, mxB1 = NINF, mnB1 = -NINF;
    float sA = 0.f, qA = 0.f, sB = 0.f, qB = 0.f;
    #pragma unroll 5
    for (int k = 0; k < KNNv; ++k) {
      float akA = rdf(atpA, k);
      float akB = rdf(atpB, k);
      int jkA = rdi(mytiA, k);
      int jkB = rdi(mytiB, k);
      float2 gA = *(const float2*)(Gb + jkA * Cv + c0);
      float2 gB = *(const float2*)(Gb + jkB * Cv + c0);
      float yA0 = akA * (gA.x - pwA0);
      float yA1 = akA * (gA.y - pwA1);
      float yB0 = akB * (gB.x - pwB0);
      float yB1 = akB * (gB.y - pwB1);
      mxA0 = fmaxf(mxA0, yA0); mnA0 = fminf(mnA0, yA0);
      mxA1 = fmaxf(mxA1, yA1); mnA1 = fminf(mnA1, yA1);
      mxB0 = fmaxf(mxB0, yB0); mnB0 = fminf(mnB0, yB0);
      mxB1 = fmaxf(mxB1, yB1); mnB1 = fminf(mnB1, yB1);
      sA += yA0 + yA1;
      qA = fmaf(yA0, yA0, fmaf(yA1, yA1, qA));
      sB += yB0 + yB1;
      qB = fmaf(yB0, yB0, fmaf(yB1, yB1, qB));
    }
    float2 mselA, mselB;
    mselA.x = (ga0 >= 0.f) ? mxA0 : mnA0;
    mselA.y = (ga1 >= 0.f) ? mxA1 : mnA1;
    mselB.x = (ga0 >= 0.f) ? mxB0 : mnB0;
    mselB.y = (ga1 >= 0.f) ? mxB1 : mnB1;
    mselS[w][pe * 2 + 0][l] = mselA;
    mselS[w][pe * 2 + 1][l] = mselB;
    sAcc += sA + sB;
    qAcc += qA + qB;
  }

  // GN partials: lanes 0-31 = group 0 (ch<64), 32-63 = group 1
  float sg = sAcc, qg = qAcc;
  #pragma unroll
  for (int msk = 16; msk; msk >>= 1) {
    sg += __shfl_xor(sg, msk);
    qg += __shfl_xor(qg, msk);
  }
  if ((l & 31) == 0) partS[w * 2 + (l >> 5)] = make_float2(sg, qg);
  __syncthreads();
  if (tid == 0) {
    float s0 = 0.f, q0 = 0.f, s1 = 0.f, q1 = 0.f;
    #pragma unroll
    for (int wv = 0; wv < 8; ++wv) {
      s0 += partS[wv * 2].x;     q0 += partS[wv * 2].y;
      s1 += partS[wv * 2 + 1].x; q1 += partS[wv * 2 + 1].y;
    }
    part[bid * 2 + 0] = make_float2(s0, q0);
    part[bid * 2 + 1] = make_float2(s1, q1);
  }
  __threadfence();
  grid.sync();

  // ---------------- Phase 3: stats (deterministic across blocks) ----------
  // FIX vs R9: each batch has 128 block-partials; each lane folds TWO
  // (l and 64+l) in fixed order before the shuffle tree.
  if (w == 0) {
    #pragma unroll
    for (int g = 0; g < 2; ++g) {
      float2 pa0 = part[((b * 128) + l) * 2 + g];
      float2 pa1 = part[((b * 128) + 64 + l) * 2 + g];
      double s = (double)pa0.x + (double)pa1.x;
      double q = (double)pa0.y + (double)pa1.y;
      #pragma unroll
      for (int msk = 32; msk; msk >>= 1) {
        s += __shfl_xor(s, msk);
        q += __shfl_xor(q, msk);
      }
      if (l == 0) {
        const double cnt = 64.0 * 30.0 * 8192.0;
        double mu = s / cnt;
        double var = q / cnt - mu * mu;
        statsS[g] = make_float2((float)mu, (float)(1.0 / sqrt(var + 1e-5)));
      }
    }
  }
  __syncthreads();

  // ---------------- Phase 4: GN affine + leaky + output MLP ---------------
  float2 stg = statsS[l >> 5];
  float bet0 = beta[c0], bet1 = beta[c1];
  float2 mw0a = *(const float2*)(mlp_w + 0 * 256 + c0);
  float2 mw1a = *(const float2*)(mlp_w + 1 * 256 + c0);
  float2 mw2a = *(const float2*)(mlp_w + 2 * 256 + c0);
  float2 mw0b = *(const float2*)(mlp_w + 0 * 256 + 128 + c0);
  float2 mw1b = *(const float2*)(mlp_w + 1 * 256 + 128 + c0);
  float2 mw2b = *(const float2*)(mlp_w + 2 * 256 + 128 + c0);
  float mb = (l < 3) ? mlp_b[l] : 0.f;
  #pragma clang loop unroll(disable)
  for (int r = 0; r < 8; ++r) {
    int n = blocal * 64 + w * 8 + r;
    long row = (long)b * Nv + n;
    float2 ms = mselS[w][r][l];
    float2 fv = *(const float2*)(feature + row * Cv + c0);
    float yv0 = fmaf((ms.x - stg.x) * stg.y, ga0, bet0);
    float yv1 = fmaf((ms.y - stg.x) * stg.y, ga1, bet1);
    yv0 = (yv0 >= 0.f) ? yv0 : 0.2f * yv0;
    yv1 = (yv1 >= 0.f) ? yv1 : 0.2f * yv1;
    float p0 = yv0 * mw0a.x + yv1 * mw0a.y + fv.x * mw0b.x + fv.y * mw0b.y;
    float p1 = yv0 * mw1a.x + yv1 * mw1a.y + fv.x * mw1b.x + fv.y * mw1b.y;
    float p2 = yv0 * mw2a.x + yv1 * mw2a.y + fv.x * mw2b.x + fv.y * mw2b.y;
    float s0 = wave_sum(p0);
    float s1 = wave_sum(p1);
    float s2 = wave_sum(p2);
    if (l < 3) {
      float sv = (l == 0) ? s0 : ((l == 1) ? s1 : s2);
      out[(long)b * 3 * Nv + (long)l * Nv + n] = sv + mb;
    }
  }
}

extern "C" void kernel_launch(void* const* d_in, const int* in_sizes, int n_in,
                              void* d_out, int out_size, void* d_ws, size_t ws_size,
                              hipStream_t stream) {
  const float* points  = (const float*)d_in[0];
  const float* feature = (const float*)d_in[1];
  const float* inst    = (const float*)d_in[2];
  const float* w1      = (const float*)d_in[3];
  const float* w2      = (const float*)d_in[4];
  const float* conv_w  = (const float*)d_in[5];
  const float* gamma   = (const float*)d_in[6];
  const float* beta    = (const float*)d_in[7];
  const float* mlp_w   = (const float*)d_in[8];
  const float* mlp_b   = (const float*)d_in[9];
  float* out = (float*)d_out;

  // workspace: gn32 [0,122880) | GW [122880,245760) | part [245760,+4096)
  char* ws = (char*)d_ws;
  float* gn32  = (float*)(ws);
  float* GW    = (float*)(ws + 122880);
  float2* part = (float2*)(ws + 245760);

  void* args[] = {
    (void*)&points, (void*)&feature, (void*)&inst, (void*)&w1, (void*)&w2,
    (void*)&conv_w, (void*)&gamma, (void*)&beta, (void*)&mlp_w, (void*)&mlp_b,
    (void*)&gn32, (void*)&GW, (void*)&part, (void*)&out
  };
  hipLaunchCooperativeKernel((void*)k_all, dim3(256), dim3(512), args, 0,
                             stream);
}

// Round 11
// 162.130 us; speedup vs baseline: 1.9476x; 1.9476x over previous
//
#include <hip/hip_runtime.h>

#define Bv   2
#define Nv   8192
#define Cv   128
#define KSv  120
#define KNNv 30

// ---------------------------------------------------------------------------
// Compile-time replication of np.random.RandomState(1234).shuffle(arange(8192))
// -> first 120 entries. MT19937 + Fisher-Yates with masked rejection.
// ---------------------------------------------------------------------------
namespace mtns {
struct MTState { unsigned mt[624]; int mti; };
constexpr void mt_seed(MTState& s, unsigned seed) {
  for (int pos = 0; pos < 624; ++pos) {
    s.mt[pos] = seed;
    seed = 1812433253u * (seed ^ (seed >> 30)) + (unsigned)pos + 1u;
  }
  s.mti = 624;
}
constexpr unsigned mt_next(MTState& s) {
  if (s.mti >= 624) {
    for (int i = 0; i < 624; ++i) {
      unsigned y = (s.mt[i] & 0x80000000u) | (s.mt[(i + 1) % 624] & 0x7fffffffu);
      unsigned v = s.mt[(i + 397) % 624] ^ (y >> 1);
      s.mt[i] = (y & 1u) ? (v ^ 0x9908b0dfu) : v;
    }
    s.mti = 0;
  }
  unsigned y = s.mt[s.mti++];
  y ^= y >> 11;
  y ^= (y << 7) & 0x9d2c5680u;
  y ^= (y << 15) & 0xefc60000u;
  y ^= y >> 18;
  return y;
}
struct IdxTable { int v[KSv]; };
constexpr IdxTable make_idx() {
  MTState st{};
  mt_seed(st, 1234u);
  int arr[Nv] = {};
  for (int i = 0; i < Nv; ++i) arr[i] = i;
  for (int i = Nv - 1; i > 0; --i) {
    unsigned mask = (unsigned)i;
    mask |= mask >> 1; mask |= mask >> 2; mask |= mask >> 4;
    mask |= mask >> 8; mask |= mask >> 16;
    unsigned j = 0;
    do { j = mt_next(st) & mask; } while (j > (unsigned)i);
    int tmp = arr[i]; arr[i] = arr[(int)j]; arr[(int)j] = tmp;
  }
  IdxTable out{};
  for (int k = 0; k < KSv; ++k) out.v[k] = arr[k];
  return out;
}
}  // namespace mtns

__constant__ mtns::IdxTable IDX = mtns::make_idx();

__device__ __forceinline__ float wave_sum(float v) {
  #pragma unroll
  for (int m = 32; m; m >>= 1) v += __shfl_xor(v, m);
  return v;
}

// Opaque barrier: keeps x*x and the add as SEPARATE f32 roundings (numpy does
// mult-then-add, no FMA, in pairwise_sum) despite contraction.
__device__ __forceinline__ float opaque(float x) {
  asm volatile("" : "+v"(x));
  return x;
}

// Wave-uniform broadcasts on the VALU path (ignores exec mask).
__device__ __forceinline__ float rdf(float v, int k) {
  return __int_as_float(__builtin_amdgcn_readlane(__float_as_int(v), k));
}
__device__ __forceinline__ int rdi(int v, int k) {
  return __builtin_amdgcn_readlane(v, k);
}

// Order-isomorphic u64 sort key for (dist desc, index asc) stable order:
// key_j > key_i  <=>  d_j > d_i || (d_j == d_i && j < i).   [verified R10]
// ord32 monotone f32->u32; +/-0 mix impossible (d = dot - 1.0f -> only +0),
// no NaNs. Bit-exact invertible (decode below).
__device__ __forceinline__ unsigned long long mkkey(float d, int t) {
  unsigned u = __float_as_uint(d);
  unsigned m = (unsigned)((int)u >> 31);
  unsigned o = u ^ (m | 0x80000000u);
  return (((unsigned long long)o) << 7) | (unsigned)(119 - t);
}

// npyv reduce tree (identical op order to verified R4/R7/R8 kernels)
__device__ __forceinline__ float npyv_reduce(const float4* a) {
  float4 h0, h1, h;
  h0.x = a[0].x + a[2].x; h0.y = a[0].y + a[2].y;
  h0.z = a[0].z + a[2].z; h0.w = a[0].w + a[2].w;
  h1.x = a[1].x + a[3].x; h1.y = a[1].y + a[3].y;
  h1.z = a[1].z + a[3].z; h1.w = a[1].w + a[3].w;
  h.x = h0.x + h1.x; h.y = h0.y + h1.y; h.z = h0.z + h1.z; h.w = h0.w + h1.w;
  float sx = h.x + h.z;
  float sy = h.y + h.w;
  return sx + sy;
}

// ---------------------------------------------------------------------------
// k0: per sampled row (b, kp): numpy-pairwise f32 norm; gn32 = row / nrm
// (IEEE f32 div); G[b,kp,o] = feat_s . conv_w[o,:128] + key_pt . conv_w[o,128:]
// Also zeroes the k2 ticket counter. [verified R8]
// ---------------------------------------------------------------------------
__global__ void k0_prepare(const float* __restrict__ points,
                           const float* __restrict__ feature,
                           const float* __restrict__ inst,
                           const float* __restrict__ conv_w,
                           float* __restrict__ gn32W,
                           float* __restrict__ GW,
                           int* __restrict__ counter) {
  int bk = blockIdx.x;
  int b = bk / KSv, kp = bk % KSv;
  int jg = IDX.v[kp];
  int t = threadIdx.x;
  if (bk == 0 && t == 0) *counter = 0;
  __shared__ float featS[Cv];
  __shared__ float rowS[Cv];
  __shared__ float ptS[3];
  __shared__ float nAcc[8];
  __shared__ float nrmSh;
  long rowi = (long)b * Nv + jg;
  float iv = inst[rowi * Cv + t];
  rowS[t] = iv;
  featS[t] = feature[rowi * Cv + t];
  if (t < 3) ptS[t] = points[rowi * 3 + t];
  __syncthreads();
  if (t < 8) {
    float x0 = rowS[t];
    float acc = opaque(x0 * x0);
    #pragma unroll
    for (int i = 1; i < 16; ++i) {
      float xv = rowS[8 * i + t];
      acc = acc + opaque(xv * xv);
    }
    nAcc[t] = acc;
  }
  __syncthreads();
  if (t == 0) {
    float res = ((nAcc[0] + nAcc[1]) + (nAcc[2] + nAcc[3])) +
                ((nAcc[4] + nAcc[5]) + (nAcc[6] + nAcc[7]));
    nrmSh = sqrtf(res);
  }
  __syncthreads();
  gn32W[(b * KSv + kp) * Cv + t] = iv / nrmSh;
  const float* cw = conv_w + t * 131;
  float acc = 0.f;
  #pragma unroll 8
  for (int c = 0; c < Cv; ++c) acc = fmaf(featS[c], cw[c], acc);
  acc = fmaf(ptS[0], cw[128], fmaf(ptS[1], cw[129], fmaf(ptS[2], cw[130], acc)));
  GW[(b * KSv + kp) * Cv + t] = acc;
}

// ---------------------------------------------------------------------------
// k2: wave-per-ROW-PAIR main kernel (R8 structure, verified). 1024 blocks x
// 512 threads (8 waves); each wave processes 2 rows simultaneously through
// the paired dot. SELECTION CHANGE vs R8: instead of the O(120^2) LDS rank
// loop, a 128-element wave-wide bitonic sort (2 slots/lane, 28 layers) on
// the R10-verified u64 keys; after the sort lanes 0..29 (slot 0) hold the
// top-30 in lax.top_k order, decoded bit-exactly back to (dist, index).
// Stats via threadfence+ticket last-block f64 reduction [verified R8].
// ---------------------------------------------------------------------------
__global__ __launch_bounds__(512, 4) void k2_main(
    const float* __restrict__ points,
    const float* __restrict__ inst,
    const float* __restrict__ w1,
    const float* __restrict__ w2,
    const float* __restrict__ conv_w,
    const float* __restrict__ gamma,
    const float* __restrict__ gn32,
    const float* __restrict__ GW,
    float* __restrict__ Msel,
    float2* __restrict__ part,
    int* __restrict__ counter,
    float2* __restrict__ stats) {
  __shared__ float4 gnS[KSv * 32];   // 61440 B, XOR-swizzled rows
  __shared__ float sc[8 * 256];      // 8192 B: per-wave scratch (fnA|fnB)
  __shared__ float2 partS[16];
  __shared__ int lastFlag;

  int bid = blockIdx.x;
  int b = bid >> 9;                  // 512 blocks per batch
  int chunk = bid & 511;             // 16 rows per block
  int tid = threadIdx.x;
  int w = tid >> 6, l = tid & 63;

  const float4* gnG = (const float4*)(gn32 + (long)b * KSv * Cv);
  for (int i = tid; i < KSv * 32; i += 512) {
    int kp = i >> 5, c4 = i & 31;
    gnS[kp * 32 + (c4 ^ (kp & 31))] = gnG[i];
  }
  __syncthreads();

  float* wb = sc + w * 256;          // wave-private scratch
  float* fnA = wb;                   // 128: row A (raw, then fn)
  float* fnB = wb + 128;             // 128: row B

  int c0 = 2 * l;
  int nA = chunk * 16 + 2 * w;
  long rowA = (long)b * Nv + nA;
  long rowB = rowA + 1;
  const float* Gb = GW + (long)b * KSv * Cv;
  const float NINF = -__builtin_inff();

  // ---- stage raw inst rows ----
  float2 ivA = *(const float2*)(inst + rowA * Cv + c0);
  float2 ivB = *(const float2*)(inst + rowB * Cv + c0);
  ((float2*)fnA)[l] = ivA;
  ((float2*)fnB)[l] = ivB;
  __builtin_amdgcn_wave_barrier();

  // ---- numpy pairwise norms: lanes 0-7 -> A accs, 8-15 -> B accs ----
  float acc = 0.f;
  if (l < 16) {
    const float* xr = (l < 8) ? fnA : fnB;
    int j = l & 7;
    float x0 = xr[j];
    acc = opaque(x0 * x0);
    #pragma unroll
    for (int i = 1; i < 16; ++i) {
      float xv = xr[8 * i + j];
      acc = acc + opaque(xv * xv);
    }
  }
  float nrmA = sqrtf(((rdf(acc, 0) + rdf(acc, 1)) + (rdf(acc, 2) + rdf(acc, 3))) +
                     ((rdf(acc, 4) + rdf(acc, 5)) + (rdf(acc, 6) + rdf(acc, 7))));
  float nrmB = sqrtf(((rdf(acc, 8) + rdf(acc, 9)) + (rdf(acc, 10) + rdf(acc, 11))) +
                     ((rdf(acc, 12) + rdf(acc, 13)) + (rdf(acc, 14) + rdf(acc, 15))));
  __builtin_amdgcn_wave_barrier();
  float2 fA2, fB2;
  fA2.x = ivA.x / nrmA; fA2.y = ivA.y / nrmA;   // IEEE f32 div = np fn bits
  fB2.x = ivB.x / nrmB; fB2.y = ivB.y / nrmB;
  ((float2*)fnA)[l] = fA2;
  ((float2*)fnB)[l] = fB2;
  __builtin_amdgcn_wave_barrier();

  // ---- paired npyv dots: lane l scores key rows t0=l, t1=64+l (l<56) ----
  const float4* fA4 = (const float4*)fnA;
  const float4* fB4 = (const float4*)fnB;
  int sw = l & 31;
  const float4* g0r = gnS + l * 32;
  int r1 = 64 + l; if (r1 > KSv - 1) r1 = KSv - 1;   // clamp; d1 unused l>=56
  const float4* g1r = gnS + r1 * 32;
  float4 aA0[4], aA1[4], aB0[4], aB1[4];
  #pragma unroll
  for (int i = 0; i < 4; ++i) {
    aA0[i] = float4{0,0,0,0}; aA1[i] = float4{0,0,0,0};
    aB0[i] = float4{0,0,0,0}; aB1[i] = float4{0,0,0,0};
  }
  #pragma unroll 4
  for (int c4 = 0; c4 < 32; ++c4) {
    float4 fa = fA4[c4];
    float4 fb = fB4[c4];
    float4 g0 = g0r[c4 ^ sw];
    float4 g1 = g1r[c4 ^ sw];
    int m = c4 & 3;
    aA0[m].x = fmaf(g0.x, fa.x, aA0[m].x); aA0[m].y = fmaf(g0.y, fa.y, aA0[m].y);
    aA0[m].z = fmaf(g0.z, fa.z, aA0[m].z); aA0[m].w = fmaf(g0.w, fa.w, aA0[m].w);
    aB0[m].x = fmaf(g0.x, fb.x, aB0[m].x); aB0[m].y = fmaf(g0.y, fb.y, aB0[m].y);
    aB0[m].z = fmaf(g0.z, fb.z, aB0[m].z); aB0[m].w = fmaf(g0.w, fb.w, aB0[m].w);
    aA1[m].x = fmaf(g1.x, fa.x, aA1[m].x); aA1[m].y = fmaf(g1.y, fa.y, aA1[m].y);
    aA1[m].z = fmaf(g1.z, fa.z, aA1[m].z); aA1[m].w = fmaf(g1.w, fa.w, aA1[m].w);
    aB1[m].x = fmaf(g1.x, fb.x, aB1[m].x); aB1[m].y = fmaf(g1.y, fb.y, aB1[m].y);
    aB1[m].z = fmaf(g1.z, fb.z, aB1[m].z); aB1[m].w = fmaf(g1.w, fb.w, aB1[m].w);
  }
  float d0A = npyv_reduce(aA0) - 1.0f;
  float d1A = npyv_reduce(aA1) - 1.0f;
  float d0B = npyv_reduce(aB0) - 1.0f;
  float d1B = npyv_reduce(aB1) - 1.0f;

  // u64 sort keys; invalid slot1 (l>=56) = 0 (below every real key)
  unsigned long long kA0 = mkkey(d0A, l);
  unsigned long long kB0 = mkkey(d0B, l);
  unsigned long long kA1 = (l < 56) ? mkkey(d1A, 64 + l) : 0ull;
  unsigned long long kB1 = (l < 56) ? mkkey(d1B, 64 + l) : 0ull;

  // ---- 128-element bitonic sort DESCENDING by key (element e = slot*64+l).
  // dir(e) = ((e & kk)==0) -> descending block; CE keeps max at the lower
  // index when dir==first. 28 layers; j==64 layer is the in-lane slot swap.
  #pragma unroll
  for (int s = 1; s <= 7; ++s) {
    const int kk = 1 << s;
    #pragma unroll
    for (int j = kk >> 1; j >= 1; j >>= 1) {
      if (j == 64) {
        unsigned long long t;
        if (kA1 > kA0) { t = kA0; kA0 = kA1; kA1 = t; }
        if (kB1 > kB0) { t = kB0; kB0 = kB1; kB1 = t; }
      } else {
        const bool first = ((l & j) == 0);
        const bool dir0 = ((l & kk) == 0);
        const bool dir1 = (((64 + l) & kk) == 0);
        unsigned long long p;
        p = __shfl_xor(kA0, j);
        kA0 = (((dir0 == first)) == (p > kA0)) ? p : kA0;
        p = __shfl_xor(kA1, j);
        kA1 = (((dir1 == first)) == (p > kA1)) ? p : kA1;
        p = __shfl_xor(kB0, j);
        kB0 = (((dir0 == first)) == (p > kB0)) ? p : kB0;
        p = __shfl_xor(kB1, j);
        kB1 = (((dir1 == first)) == (p > kB1)) ? p : kB1;
      }
    }
  }

  // lanes 0..29 slot0 now hold top-30 in (d desc, idx asc) order; decode
  // bit-exactly: o -> u (inverse of ord32), idx = 119 - low7.
  unsigned oA = (unsigned)(kA0 >> 7);
  unsigned uA = (oA & 0x80000000u) ? (oA ^ 0x80000000u) : ~oA;
  float mytvA = __uint_as_float(uA);
  int mytiA = 119 - (int)((unsigned)kA0 & 127u);
  unsigned oB = (unsigned)(kB0 >> 7);
  unsigned uB = (oB & 0x80000000u) ? (oB ^ 0x80000000u) : ~oB;
  float mytvB = __uint_as_float(uB);
  int mytiB = 119 - (int)((unsigned)kB0 & 127u);

  // ---- a = relu(W1 . topk) ; a2 = W2 . a  (readlane broadcasts; R8) ----
  float aA = 0.f, aB = 0.f;
  if (l < KNNv) {
    const float* w1r = w1 + l * KNNv;
    #pragma unroll 6
    for (int k = 0; k < KNNv; ++k) {
      float w1k = w1r[k];
      aA = fmaf(rdf(mytvA, k), w1k, aA);
      aB = fmaf(rdf(mytvB, k), w1k, aB);
    }
    aA = fmaxf(aA, 0.f);
    aB = fmaxf(aB, 0.f);
  }
  float a2A = NINF, a2B = NINF;
  if (l < KNNv) {
    const float* w2r = w2 + l * KNNv;
    float sA2 = 0.f, sB2 = 0.f;
    #pragma unroll 6
    for (int o = 0; o < KNNv; ++o) {
      float w2o = w2r[o];
      sA2 = fmaf(rdf(aA, o), w2o, sA2);
      sB2 = fmaf(rdf(aB, o), w2o, sB2);
    }
    a2A = sA2; a2B = sB2;
  }

  // ---- softmax over 30 (shuffle trees; R8) ----
  float mA = a2A, mB = a2B;
  #pragma unroll
  for (int msk = 32; msk; msk >>= 1) {
    mA = fmaxf(mA, __shfl_xor(mA, msk));
    mB = fmaxf(mB, __shfl_xor(mB, msk));
  }
  float evA = (l < KNNv) ? __expf(a2A - mA) : 0.f;
  float evB = (l < KNNv) ? __expf(a2B - mB) : 0.f;
  float invA = 1.0f / wave_sum(evA);
  float invB = 1.0f / wave_sum(evB);
  float atpA = evA * invA;
  float atpB = evB * invB;

  // ---- y scan: y_k = attn_k * (G[j_k][c] - PW_c)  (R8) ----
  float pA0 = points[rowA * 3 + 0], pA1 = points[rowA * 3 + 1],
        pA2 = points[rowA * 3 + 2];
  float pB0 = points[rowB * 3 + 0], pB1 = points[rowB * 3 + 1],
        pB2 = points[rowB * 3 + 2];
  int c1 = c0 + 1;
  float cwa0 = conv_w[c0 * 131 + 128], cwb0 = conv_w[c0 * 131 + 129],
        cwc0 = conv_w[c0 * 131 + 130];
  float cwa1 = conv_w[c1 * 131 + 128], cwb1 = conv_w[c1 * 131 + 129],
        cwc1 = conv_w[c1 * 131 + 130];
  float pwA0 = fmaf(pA0, cwa0, fmaf(pA1, cwb0, pA2 * cwc0));
  float pwA1 = fmaf(pA0, cwa1, fmaf(pA1, cwb1, pA2 * cwc1));
  float pwB0 = fmaf(pB0, cwa0, fmaf(pB1, cwb0, pB2 * cwc0));
  float pwB1 = fmaf(pB0, cwa1, fmaf(pB1, cwb1, pB2 * cwc1));
  float mxA0 = NINF, mnA0 = -NINF, mxA1 = NINF, mnA1 = -NINF;
  float mxB0 = NINF, mnB0 = -NINF, mxB1 = NINF, mnB1 = -NINF;
  float sA = 0.f, qA = 0.f, sB = 0.f, qB = 0.f;
  #pragma unroll 5
  for (int k = 0; k < KNNv; ++k) {
    float akA = rdf(atpA, k);
    float akB = rdf(atpB, k);
    int jkA = rdi(mytiA, k);
    int jkB = rdi(mytiB, k);
    float2 gA = *(const float2*)(Gb + jkA * Cv + c0);
    float2 gB = *(const float2*)(Gb + jkB * Cv + c0);
    float yA0 = akA * (gA.x - pwA0);
    float yA1 = akA * (gA.y - pwA1);
    float yB0 = akB * (gB.x - pwB0);
    float yB1 = akB * (gB.y - pwB1);
    mxA0 = fmaxf(mxA0, yA0); mnA0 = fminf(mnA0, yA0);
    mxA1 = fmaxf(mxA1, yA1); mnA1 = fminf(mnA1, yA1);
    mxB0 = fmaxf(mxB0, yB0); mnB0 = fminf(mnB0, yB0);
    mxB1 = fmaxf(mxB1, yB1); mnB1 = fminf(mnB1, yB1);
    sA += yA0 + yA1;
    qA = fmaf(yA0, yA0, fmaf(yA1, yA1, qA));
    sB += yB0 + yB1;
    qB = fmaf(yB0, yB0, fmaf(yB1, yB1, qB));
  }
  float ga0 = gamma[c0], ga1 = gamma[c1];
  float2 mselA, mselB;
  mselA.x = (ga0 >= 0.f) ? mxA0 : mnA0;
  mselA.y = (ga1 >= 0.f) ? mxA1 : mnA1;
  mselB.x = (ga0 >= 0.f) ? mxB0 : mnB0;
  mselB.y = (ga1 >= 0.f) ? mxB1 : mnB1;
  *(float2*)(Msel + rowA * Cv + c0) = mselA;
  *(float2*)(Msel + rowB * Cv + c0) = mselB;

  // ---- GN partials + ticket stats (R8, verified) ----
  float sg = sA + sB, qg = qA + qB;
  #pragma unroll
  for (int msk = 16; msk; msk >>= 1) {
    sg += __shfl_xor(sg, msk);
    qg += __shfl_xor(qg, msk);
  }
  if ((l & 31) == 0) partS[w * 2 + (l >> 5)] = make_float2(sg, qg);
  __syncthreads();
  if (tid == 0) {
    float s0 = 0.f, q0 = 0.f, s1 = 0.f, q1 = 0.f;
    #pragma unroll
    for (int wv = 0; wv < 8; ++wv) {
      s0 += partS[wv * 2].x;     q0 += partS[wv * 2].y;
      s1 += partS[wv * 2 + 1].x; q1 += partS[wv * 2 + 1].y;
    }
    part[bid * 2 + 0] = make_float2(s0, q0);
    part[bid * 2 + 1] = make_float2(s1, q1);
    __threadfence();
    int old = atomicAdd(counter, 1);
    lastFlag = (old == (int)gridDim.x - 1);
  }
  __syncthreads();
  if (lastFlag && w < 4) {
    // wave w handles (bb = w>>1, g = w&1); fixed-order f64 -> deterministic
    int bb = w >> 1, g = w & 1;
    double s = 0.0, q = 0.0;
    #pragma unroll
    for (int i = 0; i < 8; ++i) {
      float2 p = part[(bb * 512 + l + 64 * i) * 2 + g];
      s += (double)p.x;
      q += (double)p.y;
    }
    #pragma unroll
    for (int msk = 32; msk; msk >>= 1) {
      s += __shfl_xor(s, msk);
      q += __shfl_xor(q, msk);
    }
    if (l == 0) {
      const double cnt = 64.0 * 30.0 * 8192.0;
      double mu = s / cnt;
      double var = q / cnt - mu * mu;
      stats[bb * 2 + g] = make_float2((float)mu, (float)(1.0 / sqrt(var + 1e-5)));
    }
  }
}

// ---------------------------------------------------------------------------
// k4: GN affine + leaky on the gamma-selected pooled channel, then 3x256
// output MLP. 2 rows per 256-thread block. [verified R8]
// ---------------------------------------------------------------------------
__global__ __launch_bounds__(256) void k4_out(
    const float* __restrict__ feature,
    const float* __restrict__ gamma,
    const float* __restrict__ beta,
    const float* __restrict__ mlp_w,
    const float* __restrict__ mlp_b,
    const float* __restrict__ Msel,
    const float2* __restrict__ stats,
    float* __restrict__ out) {
  int rr = threadIdx.x >> 7;
  int t = threadIdx.x & 127;
  long row = (long)blockIdx.x * 2 + rr;
  int b = (int)(row >> 13), n = (int)(row & (Nv - 1));
  int g = t >> 6;
  float2 st = stats[b * 2 + g];
  float gam = gamma[t], bet = beta[t];
  float M = Msel[row * Cv + t];
  float yv = fmaf((M - st.x) * st.y, gam, bet);
  yv = (yv >= 0.f) ? yv : 0.2f * yv;
  float fv = feature[row * Cv + t];
  float o0 = yv * mlp_w[0 * 256 + t] + fv * mlp_w[0 * 256 + 128 + t];
  float o1 = yv * mlp_w[1 * 256 + t] + fv * mlp_w[1 * 256 + 128 + t];
  float o2 = yv * mlp_w[2 * 256 + t] + fv * mlp_w[2 * 256 + 128 + t];
  o0 = wave_sum(o0);
  o1 = wave_sum(o1);
  o2 = wave_sum(o2);
  __shared__ float red[2][2][3];
  if ((t & 63) == 0) {
    red[rr][t >> 6][0] = o0; red[rr][t >> 6][1] = o1; red[rr][t >> 6][2] = o2;
  }
  __syncthreads();
  if (t < 3)
    out[(long)b * 3 * Nv + (long)t * Nv + n] =
        red[rr][0][t] + red[rr][1][t] + mlp_b[t];
}

extern "C" void kernel_launch(void* const* d_in, const int* in_sizes, int n_in,
                              void* d_out, int out_size, void* d_ws, size_t ws_size,
                              hipStream_t stream) {
  const float* points  = (const float*)d_in[0];
  const float* feature = (const float*)d_in[1];
  const float* inst    = (const float*)d_in[2];
  const float* w1      = (const float*)d_in[3];
  const float* w2      = (const float*)d_in[4];
  const float* conv_w  = (const float*)d_in[5];
  const float* gamma   = (const float*)d_in[6];
  const float* beta    = (const float*)d_in[7];
  const float* mlp_w   = (const float*)d_in[8];
  const float* mlp_b   = (const float*)d_in[9];
  float* out = (float*)d_out;

  // workspace layout (bytes):
  //   gn32    [0,       122880)        2*120*128 f32
  //   GW      [122880,  245760)        2*120*128 f32
  //   Msel    [245760,  +8MB)          2*8192*128 f32 (gamma-selected)
  //   part    [8634368, +16384)        1024*2 float2 (block partials)
  //   counter [8650752, +64)           int ticket
  //   stats   [8650816, +32)           4 float2
  char* ws = (char*)d_ws;
  float* gn32   = (float*)(ws);
  float* GW     = (float*)(ws + 122880);
  float* Msel   = (float*)(ws + 245760);
  float2* part  = (float2*)(ws + 8634368);
  int* counter  = (int*)(ws + 8650752);
  float2* stats = (float2*)(ws + 8650816);

  k0_prepare<<<dim3(Bv * KSv), dim3(128), 0, stream>>>(points, feature, inst,
                                                       conv_w, gn32, GW, counter);
  k2_main<<<dim3(1024), dim3(512), 0, stream>>>(points, inst, w1, w2, conv_w,
                                                gamma, gn32, GW, Msel, part,
                                                counter, stats);
  k4_out<<<dim3(Bv * Nv / 2), dim3(256), 0, stream>>>(feature, gamma, beta,
                                                      mlp_w, mlp_b, Msel,
                                                      stats, out);
}